// Round 18
// baseline (136.628 us; speedup 1.0000x reference)
//
#include <hip/hip_runtime.h>
#include <stdint.h>

typedef unsigned short u16;
typedef __bf16 bf16x8 __attribute__((ext_vector_type(8)));
typedef float f32x4 __attribute__((ext_vector_type(4)));
typedef float f32x16 __attribute__((ext_vector_type(16)));

__device__ __forceinline__ u16 f2bf(float f) {
  uint32_t u = __builtin_bit_cast(uint32_t, f);
  u += 0x7FFFu + ((u >> 16) & 1u);
  return (u16)(u >> 16);
}
__device__ __forceinline__ float bf2f(u16 v) {
  return __builtin_bit_cast(float, ((uint32_t)v) << 16);
}

#if __has_builtin(__builtin_amdgcn_exp2f)
__device__ __forceinline__ float exp2_fast(float x) { return __builtin_amdgcn_exp2f(x); }
#else
__device__ __forceinline__ float exp2_fast(float x) { return exp2f(x); }
#endif

__device__ __forceinline__ void gload_lds16(const u16* g, u16* l) {
  __builtin_amdgcn_global_load_lds(
      (const __attribute__((address_space(1))) uint32_t*)g,
      (__attribute__((address_space(3))) uint32_t*)l, 16, 0, 0);
}

__device__ __forceinline__ uint32_t cvtpk(float lo, float hi) {
  uint32_t r;
  asm("v_cvt_pk_bf16_f32 %0, %1, %2" : "=v"(r) : "v"(lo), "v"(hi));
  return r;
}
// v_permlane32_swap_b32: a.row1 <-> b.row0  (rows = 32-lane halves)
__device__ __forceinline__ void plswap(uint32_t& a, uint32_t& b) {
  asm volatile("v_permlane32_swap_b32 %0, %1" : "+v"(a), "+v"(b));
}

// ---------------- fused prep ----------------
// [0,4096): x->bf16 ; [4096,7168): WqkvT ; [7168,8192): WoutT ; [8192,8448): cond proj
__global__ __launch_bounds__(256) void prep_kernel(
    const float* __restrict__ x, const float* __restrict__ Wqkv,
    const float* __restrict__ Wout, const float* __restrict__ label,
    const float* __restrict__ Wk, const float* __restrict__ Wv,
    u16* __restrict__ xb, u16* __restrict__ WqkvT, u16* __restrict__ WoutT,
    u16* __restrict__ ek, u16* __restrict__ ev, float qscale) {
  const int b = blockIdx.x;
  if (b < 4096) {
    int i = (b * 256 + threadIdx.x) * 8;
    float4 a = *(const float4*)(x + i);
    float4 c = *(const float4*)(x + i + 4);
    union { u16 u[8]; uint4 v; } r;
    r.u[0] = f2bf(a.x); r.u[1] = f2bf(a.y); r.u[2] = f2bf(a.z); r.u[3] = f2bf(a.w);
    r.u[4] = f2bf(c.x); r.u[5] = f2bf(c.y); r.u[6] = f2bf(c.z); r.u[7] = f2bf(c.w);
    *(uint4*)(xb + i) = r.v;
  } else if (b < 7168) {
    int id = (b - 4096) * 256 + threadIdx.x;
    int k = id & 511, nn = id >> 9;
    float v = Wqkv[(size_t)k * 1536 + nn];
    if (nn < 512) v *= qscale;
    WqkvT[id] = f2bf(v);
  } else if (b < 8192) {
    int id = (b - 7168) * 256 + threadIdx.x;
    int k = id & 511, nn = id >> 9;
    WoutT[id] = f2bf(Wout[(size_t)k * 512 + nn]);
  } else {
    // cond proj: 256 blocks = 2 (k/v) x 16 rows x 8 col-chunks; 4-way K-split + LDS reduce
    __shared__ float sdata[256];
    const int bb = b - 8192;
    const int chunk = bb & 7, row = (bb >> 3) & 15;
    const float* W = (bb & 128) ? Wv : Wk;
    u16* o = (bb & 128) ? ev : ek;
    const int tid = threadIdx.x;
    const int col = chunk * 64 + (tid & 63);
    const int ks = tid >> 6;  // 0..3, 128 k each
    const float* lr = label + row * 512 + ks * 128;
    const float* wp = W + (size_t)(ks * 128) * 512 + col;
    float acc = 0.f;
#pragma unroll 8
    for (int i = 0; i < 128; ++i)
      acc = fmaf(lr[i], wp[(size_t)i * 512], acc);
    sdata[tid] = acc;
    __syncthreads();
    if (tid < 64) {
      float t = sdata[tid] + sdata[tid + 64] + sdata[tid + 128] + sdata[tid + 192];
      o[row * 512 + chunk * 64 + tid] = f2bf(t);
    }
  }
}

// ---------------- GEMM v5: BM=128 x BN(192|128), BK=64, 4 waves, 2 blocks/CU ----------------
// MODE 0: wave 128x48 (1M x 4N). MODE 1: wave 64x64 (2M x 2N).
template <int MODE>
__global__ __launch_bounds__(256, 2) void gemm_bt_kernel(
    const u16* __restrict__ A, const u16* __restrict__ B,
    u16* __restrict__ OQ, u16* __restrict__ OKb, u16* __restrict__ OVT,
    float* __restrict__ OF, int K, int N) {
  constexpr int BN = (MODE == 0) ? 192 : 128;
  constexpr int NA = (MODE == 0) ? 8 : 4;   // A fragments per wave
  constexpr int NB = (MODE == 0) ? 3 : 4;   // B fragments per wave
  constexpr int A_ISS = 4;
  constexpr int B_ISS = BN / 32;            // 6 | 4
  constexpr int NBY = (MODE == 0) ? 8 : 4;

  __shared__ __align__(16) u16 As[2][128 * 64];
  __shared__ __align__(16) u16 Bs[2][BN * 64];

  const int tid = threadIdx.x;  // 0..255
  const int w = tid >> 6, lane = tid & 63;
  const int l15 = lane & 15, lg = lane >> 4;

  const int q8 = gridDim.x >> 3;
  const int wg = (blockIdx.x & 7) * q8 + (blockIdx.x >> 3);
  const int bx = wg / NBY, by = wg % NBY;

  const int srow = lane >> 3;
  const int schunk = (lane & 7) ^ srow;
  const u16* Ag = A + (size_t)(bx * 128 + srow) * K + schunk * 8;
  const u16* Bg = B + (size_t)(by * BN + srow) * K + schunk * 8;

  int aoff[NA][2], boff[NB][2];
#pragma unroll
  for (int mi = 0; mi < NA; ++mi)
#pragma unroll
    for (int ks = 0; ks < 2; ++ks) {
      const int row = ((MODE == 0) ? 0 : (w >> 1) * 64) + mi * 16 + l15;
      aoff[mi][ks] = row * 64 + (((ks * 4 + lg) ^ (row & 7)) * 8);
    }
#pragma unroll
  for (int ni = 0; ni < NB; ++ni)
#pragma unroll
    for (int ks = 0; ks < 2; ++ks) {
      const int row = ((MODE == 0) ? w * 48 : (w & 1) * 64) + ni * 16 + l15;
      boff[ni][ks] = row * 64 + (((ks * 4 + lg) ^ (row & 7)) * 8);
    }

  f32x4 acc[NA][NB] = {};

  const int nt = K >> 6;  // 8
#define STAGE(buf, k0)                                                        \
  {                                                                           \
    _Pragma("unroll") for (int i = 0; i < A_ISS; ++i) {                       \
      const int j = i * 4 + w;                                                \
      gload_lds16(Ag + (k0) + (size_t)(j * 8) * K, &As[buf][(j * 8) * 64]);   \
    }                                                                         \
    _Pragma("unroll") for (int i = 0; i < B_ISS; ++i) {                       \
      const int j = i * 4 + w;                                                \
      gload_lds16(Bg + (k0) + (size_t)(j * 8) * K, &Bs[buf][(j * 8) * 64]);   \
    }                                                                         \
  }
#define COMPUTE(cb)                                                           \
  {                                                                           \
    const u16* Ab = &As[cb][0];                                               \
    const u16* Bb = &Bs[cb][0];                                               \
    _Pragma("unroll") for (int ks = 0; ks < 2; ++ks) {                        \
      bf16x8 a[NA], b[NB];                                                    \
      _Pragma("unroll") for (int mi = 0; mi < NA; ++mi)                       \
          a[mi] = *(const bf16x8*)&Ab[aoff[mi][ks]];                          \
      _Pragma("unroll") for (int ni = 0; ni < NB; ++ni)                       \
          b[ni] = *(const bf16x8*)&Bb[boff[ni][ks]];                          \
      __builtin_amdgcn_s_setprio(1);                                          \
      _Pragma("unroll") for (int mi = 0; mi < NA; ++mi)                       \
          _Pragma("unroll") for (int ni = 0; ni < NB; ++ni)                   \
              acc[mi][ni] = __builtin_amdgcn_mfma_f32_16x16x32_bf16(           \
                  a[mi], b[ni], acc[mi][ni], 0, 0, 0);                        \
      __builtin_amdgcn_s_setprio(0);                                          \
    }                                                                         \
  }

  STAGE(0, 0);
  STAGE(1, 64);

  for (int t = 0; t < nt - 1; ++t) {
    if constexpr (A_ISS + B_ISS == 10)
      asm volatile("s_waitcnt vmcnt(10)" ::: "memory");
    else
      asm volatile("s_waitcnt vmcnt(8)" ::: "memory");
    __builtin_amdgcn_s_barrier();
    __builtin_amdgcn_sched_barrier(0);
    COMPUTE(t & 1);
    if (t + 2 < nt) {
      __builtin_amdgcn_s_barrier();
      __builtin_amdgcn_sched_barrier(0);
      STAGE(t & 1, (t + 2) * 64);
    }
  }
  asm volatile("s_waitcnt vmcnt(0)" ::: "memory");
  __builtin_amdgcn_s_barrier();
  __builtin_amdgcn_sched_barrier(0);
  COMPUTE((nt - 1) & 1);
#undef STAGE
#undef COMPUTE

  if constexpr (MODE == 1) {
    const int row0 = bx * 128 + (w >> 1) * 64 + lg * 4;
#pragma unroll
    for (int mi = 0; mi < NA; ++mi)
#pragma unroll
      for (int ni = 0; ni < NB; ++ni) {
        int col = by * BN + (w & 1) * 64 + ni * 16 + l15;
#pragma unroll
        for (int r = 0; r < 4; ++r)
          OF[(size_t)(row0 + mi * 16 + r) * N + col] = acc[mi][ni][r];
      }
  } else {
    const int row0 = bx * 128 + lg * 4;
#pragma unroll
    for (int mi = 0; mi < NA; ++mi)
#pragma unroll
      for (int ni = 0; ni < NB; ++ni) {
        const int gcol = by * BN + w * 48 + ni * 16 + l15;
        const int sect = gcol >> 9;      // 0=q, 1=k, 2=v
        const int colL = gcol & 511;
        if (sect < 2) {
          u16* O = sect ? OKb : OQ;
#pragma unroll
          for (int r = 0; r < 4; ++r)
            O[(size_t)(row0 + mi * 16 + r) * 512 + colL] = f2bf(acc[mi][ni][r]);
        } else {
          int h = colL >> 6, dh = colL & 63;
          int rr = row0 + mi * 16;
          int bn = rr >> 10, t0 = rr & 1023;
          ushort4 pk;
          pk.x = f2bf(acc[mi][ni][0]);
          pk.y = f2bf(acc[mi][ni][1]);
          pk.z = f2bf(acc[mi][ni][2]);
          pk.w = f2bf(acc[mi][ni][3]);
          *(ushort4*)&OVT[(size_t)((bn * 8 + h) * 64 + dh) * 1024 + t0] = pk;
        }
      }
  }
}

// ---------------- fused flash attention v12: LDS-free, 1-wave blocks, direct-global fragments ----------------
// grid: 2048 = 128 heads x 16 q-tiles of 64. block: 64 (1 wave, 64 q).
// No LDS, no barriers: K/V MFMA fragments loaded directly from global (L1/L2-cached;
// per-head K/V = 128KB each, XCD swizzle gives 16 heads/XCD = L2-resident).
// Addresses transcribe the round-13 LDS contents exactly; math/prologue/epilogue verbatim.
__global__ __launch_bounds__(64, 2) void attn_kernel(
    const u16* __restrict__ Qb, const u16* __restrict__ Kb, const u16* __restrict__ VTb,
    const u16* __restrict__ ekb, const u16* __restrict__ evb, u16* __restrict__ Ob) {
  const int lane = threadIdx.x;  // 0..63
  const int l31 = lane & 31, hi = lane >> 5;
  // XCD swizzle (2048 % 8 == 0, bijective): 16 heads per XCD -> K/V L2-resident
  const int lb = (blockIdx.x & 7) * 256 + (blockIdx.x >> 3);
  const int head = lb >> 4, qt = lb & 15;
  const int bn = head >> 3, h = head & 7;
  const int q0 = qt * 64;

  const u16* Kg = Kb + (size_t)(bn * 1024) * 512 + h * 64;  // + kv*512 + d
  const u16* Vg = VTb + (size_t)(head * 64) * 1024;          // + dh*1024 + t

  bf16x8 qf[2][4];
#pragma unroll
  for (int qs = 0; qs < 2; ++qs)
#pragma unroll
    for (int c = 0; c < 4; ++c)
      qf[qs][c] = *(const bf16x8*)(Qb + (size_t)(bn * 1024 + q0 + qs * 32 + l31) * 512 +
                                   h * 64 + c * 16 + hi * 8);

  bf16x8 bones1;
  {
    union { u16 u[8]; bf16x8 v; } ob;
#pragma unroll
    for (int j = 0; j < 8; ++j) ob.u[j] = (u16)0x3F80;
    bones1 = ob.v;
  }

  // ---- conditioning token prologue (round-13 verbatim) ----
  f32x16 acc[2][2];
  f32x16 acc5[2];
  {
    float dot[2] = {0.f, 0.f};
#pragma unroll
    for (int c = 0; c < 4; ++c) {
      bf16x8 ekf = *(const bf16x8*)(ekb + bn * 512 + h * 64 + c * 16 + hi * 8);
#pragma unroll
      for (int qs = 0; qs < 2; ++qs)
#pragma unroll
        for (int j = 0; j < 8; ++j)
          dot[qs] += (float)qf[qs][c][j] * (float)ekf[j];
    }
    union { u16 u[8]; bf16x8 v; } pef[2], evf[2];
#pragma unroll
    for (int qs = 0; qs < 2; ++qs) {
      uint32_t a = __builtin_bit_cast(uint32_t, dot[qs]), b = a;
      plswap(a, b);
      float part = (lane < 32) ? __builtin_bit_cast(float, b) : __builtin_bit_cast(float, a);
      float pe = exp2_fast(dot[qs] + part);
#pragma unroll
      for (int j = 0; j < 8; ++j) pef[qs].u[j] = 0;
      if (hi == 0) pef[qs].u[0] = f2bf(pe);
    }
#pragma unroll
    for (int dt = 0; dt < 2; ++dt) {
#pragma unroll
      for (int j = 0; j < 8; ++j) evf[dt].u[j] = 0;
      if (hi == 0) evf[dt].u[0] = evb[bn * 512 + h * 64 + dt * 32 + l31];
    }
    f32x16 z = {};
#pragma unroll
    for (int qs = 0; qs < 2; ++qs) {
#pragma unroll
      for (int dt = 0; dt < 2; ++dt)
        acc[qs][dt] = __builtin_amdgcn_mfma_f32_32x32x16_bf16(pef[qs].v, evf[dt].v, z, 0, 0, 0);
      acc5[qs] = __builtin_amdgcn_mfma_f32_32x32x16_bf16(pef[qs].v, bones1, z, 0, 0, 0);
    }
  }

  // ---- main loop: 16 K/V tiles of 64; no LDS, no barriers ----
  for (int jt = 0; jt < 16; ++jt) {
    const int j0 = jt * 64;

#pragma unroll
    for (int sub = 0; sub < 2; ++sub) {
      // K fragments: row kv = j0 + sub*32 + l31, d chunk c*16 + hi*8  (== LDS Kl content)
      const size_t krow = (size_t)(j0 + sub * 32 + l31) * 512;
      bf16x8 kb[4];
#pragma unroll
      for (int c = 0; c < 4; ++c)
        kb[c] = *(const bf16x8*)(Kg + krow + c * 16 + hi * 8);

      f32x16 s[2] = {};
#pragma unroll
      for (int c = 0; c < 4; ++c) {
        s[0] = __builtin_amdgcn_mfma_f32_32x32x16_bf16(kb[c], qf[0][c], s[0], 0, 0, 0);
        s[1] = __builtin_amdgcn_mfma_f32_32x32x16_bf16(kb[c], qf[1][c], s[1], 0, 0, 0);
      }

      // exp2 -> pack -> permlane -> PV A-frags (round-13 verbatim)
      bf16x8 pa[2][2];
#pragma unroll
      for (int qs = 0; qs < 2; ++qs) {
        uint32_t wd[8];
#pragma unroll
        for (int i = 0; i < 8; ++i)
          wd[i] = cvtpk(exp2_fast(s[qs][2 * i]), exp2_fast(s[qs][2 * i + 1]));
        plswap(wd[0], wd[2]);
        plswap(wd[1], wd[3]);
        plswap(wd[4], wd[6]);
        plswap(wd[5], wd[7]);
        union { uint32_t w[4]; bf16x8 v; } f0, f1;
        f0.w[0] = wd[0]; f0.w[1] = wd[1]; f0.w[2] = wd[2]; f0.w[3] = wd[3];
        f1.w[0] = wd[4]; f1.w[1] = wd[5]; f1.w[2] = wd[6]; f1.w[3] = wd[7];
        pa[qs][0] = f0.v;
        pa[qs][1] = f1.v;
      }

      // PV: V fragments direct: row dh = dt*32 + l31, t chunk (sub*4 + ch*2 + hi)*8
#pragma unroll
      for (int dt = 0; dt < 2; ++dt) {
        const size_t vrow = (size_t)(dt * 32 + l31) * 1024;
#pragma unroll
        for (int ch = 0; ch < 2; ++ch) {
          bf16x8 vb = *(const bf16x8*)(Vg + vrow + j0 + (sub * 4 + ch * 2 + hi) * 8);
#pragma unroll
          for (int qs = 0; qs < 2; ++qs)
            acc[qs][dt] = __builtin_amdgcn_mfma_f32_32x32x16_bf16(pa[qs][ch], vb, acc[qs][dt], 0, 0, 0);
        }
      }
#pragma unroll
      for (int qs = 0; qs < 2; ++qs)
#pragma unroll
        for (int ch = 0; ch < 2; ++ch)
          acc5[qs] = __builtin_amdgcn_mfma_f32_32x32x16_bf16(pa[qs][ch], bones1, acc5[qs], 0, 0, 0);
    }
  }

  // ---- normalize + store (round-13 verbatim) ----
#pragma unroll
  for (int qs = 0; qs < 2; ++qs)
#pragma unroll
    for (int r = 0; r < 16; ++r) {
      const float inv = 1.0f / acc5[qs][r];
      const int q = q0 + qs * 32 + (r & 3) + 8 * (r >> 2) + 4 * hi;
      u16* op = Ob + (size_t)(bn * 1024 + q) * 512 + h * 64 + l31;
      op[0] = f2bf(acc[qs][0][r] * inv);
      op[32] = f2bf(acc[qs][1][r] * inv);
    }
}

// ---------------- launcher ----------------
extern "C" void kernel_launch(void* const* d_in, const int* in_sizes, int n_in,
                              void* d_out, int out_size, void* d_ws, size_t ws_size,
                              hipStream_t stream) {
  (void)in_sizes; (void)n_in; (void)out_size; (void)ws_size;
  const float* x     = (const float*)d_in[0];
  const float* label = (const float*)d_in[1];
  const float* Wqkv  = (const float*)d_in[2];
  const float* Wk    = (const float*)d_in[3];
  const float* Wv    = (const float*)d_in[4];
  const float* Wout  = (const float*)d_in[5];
  float* out = (float*)d_out;

  char* ws = (char*)d_ws;
  u16* xb    = (u16*)(ws);                 // 16 MB, reused as attention-out after GEMM1
  u16* WqkvT = (u16*)(ws + 16777216);      // 1.5 MB
  u16* WoutT = (u16*)(ws + 18350080);      // 0.5 MB
  u16* ekb   = (u16*)(ws + 18874368);      // 16 KB
  u16* evb   = (u16*)(ws + 18890752);      // 16 KB
  u16* Qbuf  = (u16*)(ws + 18907136);      // 16 MB
  u16* Kbuf  = (u16*)(ws + 35684352);      // 16 MB
  u16* VTbuf = (u16*)(ws + 52461568);      // 16 MB

  const float qscale = 0.125f * 1.4426950408889634f;

  prep_kernel<<<8448, 256, 0, stream>>>(x, Wqkv, Wout, label, Wk, Wv,
                                        xb, WqkvT, WoutT, ekb, evb, qscale);

  gemm_bt_kernel<0><<<1024, 256, 0, stream>>>(xb, WqkvT, Qbuf, Kbuf, VTbuf, nullptr, 512, 1536);

  attn_kernel<<<2048, 64, 0, stream>>>(Qbuf, Kbuf, VTbuf, ekb, evb, xb);

  gemm_bt_kernel<1><<<512, 256, 0, stream>>>(xb, WoutT, nullptr, nullptr, nullptr, out, 512, 512);
}

// Round 19
// 116.184 us; speedup vs baseline: 1.1760x; 1.1760x over previous
//
#include <hip/hip_runtime.h>
#include <stdint.h>

typedef unsigned short u16;
typedef __bf16 bf16x8 __attribute__((ext_vector_type(8)));
typedef float f32x4 __attribute__((ext_vector_type(4)));
typedef float f32x16 __attribute__((ext_vector_type(16)));

__device__ __forceinline__ u16 f2bf(float f) {
  uint32_t u = __builtin_bit_cast(uint32_t, f);
  u += 0x7FFFu + ((u >> 16) & 1u);
  return (u16)(u >> 16);
}
__device__ __forceinline__ float bf2f(u16 v) {
  return __builtin_bit_cast(float, ((uint32_t)v) << 16);
}

#if __has_builtin(__builtin_amdgcn_exp2f)
__device__ __forceinline__ float exp2_fast(float x) { return __builtin_amdgcn_exp2f(x); }
#else
__device__ __forceinline__ float exp2_fast(float x) { return exp2f(x); }
#endif

__device__ __forceinline__ void gload_lds16(const u16* g, u16* l) {
  __builtin_amdgcn_global_load_lds(
      (const __attribute__((address_space(1))) uint32_t*)g,
      (__attribute__((address_space(3))) uint32_t*)l, 16, 0, 0);
}

__device__ __forceinline__ uint32_t cvtpk(float lo, float hi) {
  uint32_t r;
  asm("v_cvt_pk_bf16_f32 %0, %1, %2" : "=v"(r) : "v"(lo), "v"(hi));
  return r;
}
// v_permlane32_swap_b32: a.row1 <-> b.row0  (rows = 32-lane halves)
__device__ __forceinline__ void plswap(uint32_t& a, uint32_t& b) {
  asm volatile("v_permlane32_swap_b32 %0, %1" : "+v"(a), "+v"(b));
}

// ---------------- fused prep ----------------
// [0,4096): x->bf16 ; [4096,7168): WqkvT ; [7168,8192): WoutT ; [8192,8448): cond proj
__global__ __launch_bounds__(256) void prep_kernel(
    const float* __restrict__ x, const float* __restrict__ Wqkv,
    const float* __restrict__ Wout, const float* __restrict__ label,
    const float* __restrict__ Wk, const float* __restrict__ Wv,
    u16* __restrict__ xb, u16* __restrict__ WqkvT, u16* __restrict__ WoutT,
    u16* __restrict__ ek, u16* __restrict__ ev, float qscale) {
  const int b = blockIdx.x;
  if (b < 4096) {
    int i = (b * 256 + threadIdx.x) * 8;
    float4 a = *(const float4*)(x + i);
    float4 c = *(const float4*)(x + i + 4);
    union { u16 u[8]; uint4 v; } r;
    r.u[0] = f2bf(a.x); r.u[1] = f2bf(a.y); r.u[2] = f2bf(a.z); r.u[3] = f2bf(a.w);
    r.u[4] = f2bf(c.x); r.u[5] = f2bf(c.y); r.u[6] = f2bf(c.z); r.u[7] = f2bf(c.w);
    *(uint4*)(xb + i) = r.v;
  } else if (b < 7168) {
    int id = (b - 4096) * 256 + threadIdx.x;
    int k = id & 511, nn = id >> 9;
    float v = Wqkv[(size_t)k * 1536 + nn];
    if (nn < 512) v *= qscale;
    WqkvT[id] = f2bf(v);
  } else if (b < 8192) {
    int id = (b - 7168) * 256 + threadIdx.x;
    int k = id & 511, nn = id >> 9;
    WoutT[id] = f2bf(Wout[(size_t)k * 512 + nn]);
  } else {
    // cond proj: 256 blocks = 2 (k/v) x 16 rows x 8 col-chunks; 4-way K-split + LDS reduce
    __shared__ float sdata[256];
    const int bb = b - 8192;
    const int chunk = bb & 7, row = (bb >> 3) & 15;
    const float* W = (bb & 128) ? Wv : Wk;
    u16* o = (bb & 128) ? ev : ek;
    const int tid = threadIdx.x;
    const int col = chunk * 64 + (tid & 63);
    const int ks = tid >> 6;  // 0..3, 128 k each
    const float* lr = label + row * 512 + ks * 128;
    const float* wp = W + (size_t)(ks * 128) * 512 + col;
    float acc = 0.f;
#pragma unroll 8
    for (int i = 0; i < 128; ++i)
      acc = fmaf(lr[i], wp[(size_t)i * 512], acc);
    sdata[tid] = acc;
    __syncthreads();
    if (tid < 64) {
      float t = sdata[tid] + sdata[tid + 64] + sdata[tid + 128] + sdata[tid + 192];
      o[row * 512 + chunk * 64 + tid] = f2bf(t);
    }
  }
}

// ---------------- GEMM v5: BM=128 x BN(192|128), BK=64, 4 waves, 2 blocks/CU ----------------
// MODE 0: wave 128x48 (1M x 4N). MODE 1: wave 64x64 (2M x 2N).
template <int MODE>
__global__ __launch_bounds__(256, 2) void gemm_bt_kernel(
    const u16* __restrict__ A, const u16* __restrict__ B,
    u16* __restrict__ OQ, u16* __restrict__ OKb, u16* __restrict__ OVT,
    float* __restrict__ OF, int K, int N) {
  constexpr int BN = (MODE == 0) ? 192 : 128;
  constexpr int NA = (MODE == 0) ? 8 : 4;   // A fragments per wave
  constexpr int NB = (MODE == 0) ? 3 : 4;   // B fragments per wave
  constexpr int A_ISS = 4;
  constexpr int B_ISS = BN / 32;            // 6 | 4
  constexpr int NBY = (MODE == 0) ? 8 : 4;

  __shared__ __align__(16) u16 As[2][128 * 64];
  __shared__ __align__(16) u16 Bs[2][BN * 64];

  const int tid = threadIdx.x;  // 0..255
  const int w = tid >> 6, lane = tid & 63;
  const int l15 = lane & 15, lg = lane >> 4;

  const int q8 = gridDim.x >> 3;
  const int wg = (blockIdx.x & 7) * q8 + (blockIdx.x >> 3);
  const int bx = wg / NBY, by = wg % NBY;

  const int srow = lane >> 3;
  const int schunk = (lane & 7) ^ srow;
  const u16* Ag = A + (size_t)(bx * 128 + srow) * K + schunk * 8;
  const u16* Bg = B + (size_t)(by * BN + srow) * K + schunk * 8;

  int aoff[NA][2], boff[NB][2];
#pragma unroll
  for (int mi = 0; mi < NA; ++mi)
#pragma unroll
    for (int ks = 0; ks < 2; ++ks) {
      const int row = ((MODE == 0) ? 0 : (w >> 1) * 64) + mi * 16 + l15;
      aoff[mi][ks] = row * 64 + (((ks * 4 + lg) ^ (row & 7)) * 8);
    }
#pragma unroll
  for (int ni = 0; ni < NB; ++ni)
#pragma unroll
    for (int ks = 0; ks < 2; ++ks) {
      const int row = ((MODE == 0) ? w * 48 : (w & 1) * 64) + ni * 16 + l15;
      boff[ni][ks] = row * 64 + (((ks * 4 + lg) ^ (row & 7)) * 8);
    }

  f32x4 acc[NA][NB] = {};

  const int nt = K >> 6;  // 8
#define STAGE(buf, k0)                                                        \
  {                                                                           \
    _Pragma("unroll") for (int i = 0; i < A_ISS; ++i) {                       \
      const int j = i * 4 + w;                                                \
      gload_lds16(Ag + (k0) + (size_t)(j * 8) * K, &As[buf][(j * 8) * 64]);   \
    }                                                                         \
    _Pragma("unroll") for (int i = 0; i < B_ISS; ++i) {                       \
      const int j = i * 4 + w;                                                \
      gload_lds16(Bg + (k0) + (size_t)(j * 8) * K, &Bs[buf][(j * 8) * 64]);   \
    }                                                                         \
  }
#define COMPUTE(cb)                                                           \
  {                                                                           \
    const u16* Ab = &As[cb][0];                                               \
    const u16* Bb = &Bs[cb][0];                                               \
    _Pragma("unroll") for (int ks = 0; ks < 2; ++ks) {                        \
      bf16x8 a[NA], b[NB];                                                    \
      _Pragma("unroll") for (int mi = 0; mi < NA; ++mi)                       \
          a[mi] = *(const bf16x8*)&Ab[aoff[mi][ks]];                          \
      _Pragma("unroll") for (int ni = 0; ni < NB; ++ni)                       \
          b[ni] = *(const bf16x8*)&Bb[boff[ni][ks]];                          \
      __builtin_amdgcn_s_setprio(1);                                          \
      _Pragma("unroll") for (int mi = 0; mi < NA; ++mi)                       \
          _Pragma("unroll") for (int ni = 0; ni < NB; ++ni)                   \
              acc[mi][ni] = __builtin_amdgcn_mfma_f32_16x16x32_bf16(           \
                  a[mi], b[ni], acc[mi][ni], 0, 0, 0);                        \
      __builtin_amdgcn_s_setprio(0);                                          \
    }                                                                         \
  }

  STAGE(0, 0);
  STAGE(1, 64);

  for (int t = 0; t < nt - 1; ++t) {
    if constexpr (A_ISS + B_ISS == 10)
      asm volatile("s_waitcnt vmcnt(10)" ::: "memory");
    else
      asm volatile("s_waitcnt vmcnt(8)" ::: "memory");
    __builtin_amdgcn_s_barrier();
    __builtin_amdgcn_sched_barrier(0);
    COMPUTE(t & 1);
    if (t + 2 < nt) {
      __builtin_amdgcn_s_barrier();
      __builtin_amdgcn_sched_barrier(0);
      STAGE(t & 1, (t + 2) * 64);
    }
  }
  asm volatile("s_waitcnt vmcnt(0)" ::: "memory");
  __builtin_amdgcn_s_barrier();
  __builtin_amdgcn_sched_barrier(0);
  COMPUTE((nt - 1) & 1);
#undef STAGE
#undef COMPUTE

  if constexpr (MODE == 1) {
    const int row0 = bx * 128 + (w >> 1) * 64 + lg * 4;
#pragma unroll
    for (int mi = 0; mi < NA; ++mi)
#pragma unroll
      for (int ni = 0; ni < NB; ++ni) {
        int col = by * BN + (w & 1) * 64 + ni * 16 + l15;
#pragma unroll
        for (int r = 0; r < 4; ++r)
          OF[(size_t)(row0 + mi * 16 + r) * N + col] = acc[mi][ni][r];
      }
  } else {
    const int row0 = bx * 128 + lg * 4;
#pragma unroll
    for (int mi = 0; mi < NA; ++mi)
#pragma unroll
      for (int ni = 0; ni < NB; ++ni) {
        const int gcol = by * BN + w * 48 + ni * 16 + l15;
        const int sect = gcol >> 9;      // 0=q, 1=k, 2=v
        const int colL = gcol & 511;
        if (sect < 2) {
          u16* O = sect ? OKb : OQ;
#pragma unroll
          for (int r = 0; r < 4; ++r)
            O[(size_t)(row0 + mi * 16 + r) * 512 + colL] = f2bf(acc[mi][ni][r]);
        } else {
          int h = colL >> 6, dh = colL & 63;
          int rr = row0 + mi * 16;
          int bn = rr >> 10, t0 = rr & 1023;
          ushort4 pk;
          pk.x = f2bf(acc[mi][ni][0]);
          pk.y = f2bf(acc[mi][ni][1]);
          pk.z = f2bf(acc[mi][ni][2]);
          pk.w = f2bf(acc[mi][ni][3]);
          *(ushort4*)&OVT[(size_t)((bn * 8 + h) * 64 + dh) * 1024 + t0] = pk;
        }
      }
  }
}

// ---------------- fused flash attention (round-13 verbatim, best-known 45.2us) ----------------
// grid: 512 = 128 heads x 4 q-tiles of 256. block: 256 (4 waves x 64 q).
__global__ __launch_bounds__(256, 2) void attn_kernel(
    const u16* __restrict__ Qb, const u16* __restrict__ Kb, const u16* __restrict__ VTb,
    const u16* __restrict__ ekb, const u16* __restrict__ evb, u16* __restrict__ Ob) {
  __shared__ __align__(16) u16 Kl[64 * 64];
  __shared__ __align__(16) u16 Vl[64 * 64];

  const int tid = threadIdx.x;
  const int w = tid >> 6, lane = tid & 63;
  const int l31 = lane & 31, hi = lane >> 5;
  const int lb = (blockIdx.x & 7) * 64 + (blockIdx.x >> 3);
  const int head = lb >> 2, qt = lb & 3;
  const int bn = head >> 3, h = head & 7;
  const int q0 = qt * 256 + w * 64;

  const int sr = tid >> 3, sj = tid & 7;
  const int sdst = (sj ^ (sr & 7)) * 8;
  const u16* KgA = Kb + (size_t)(bn * 1024 + sr) * 512 + h * 64 + sj * 8;
  const u16* VgA = VTb + (size_t)(head * 64 + sr) * 1024 + sj * 8;
  u16* KlD = &Kl[sr * 64 + sdst];
  u16* VlD = &Vl[sr * 64 + sdst];

  uint4 kp0, kp1, vp0, vp1;
  {
    kp0 = *(const uint4*)(KgA);
    kp1 = *(const uint4*)(KgA + (size_t)32 * 512);
    vp0 = *(const uint4*)(VgA);
    vp1 = *(const uint4*)(VgA + (size_t)32 * 1024);
  }

  bf16x8 qf[2][4];
#pragma unroll
  for (int qs = 0; qs < 2; ++qs)
#pragma unroll
    for (int c = 0; c < 4; ++c)
      qf[qs][c] = *(const bf16x8*)(Qb + (size_t)(bn * 1024 + q0 + qs * 32 + l31) * 512 +
                                   h * 64 + c * 16 + hi * 8);

  bf16x8 bones1;
  {
    union { u16 u[8]; bf16x8 v; } ob;
#pragma unroll
    for (int j = 0; j < 8; ++j) ob.u[j] = (u16)0x3F80;
    bones1 = ob.v;
  }

  f32x16 acc[2][2];
  f32x16 acc5[2];
  {
    float dot[2] = {0.f, 0.f};
#pragma unroll
    for (int c = 0; c < 4; ++c) {
      bf16x8 ekf = *(const bf16x8*)(ekb + bn * 512 + h * 64 + c * 16 + hi * 8);
#pragma unroll
      for (int qs = 0; qs < 2; ++qs)
#pragma unroll
        for (int j = 0; j < 8; ++j)
          dot[qs] += (float)qf[qs][c][j] * (float)ekf[j];
    }
    union { u16 u[8]; bf16x8 v; } pef[2], evf[2];
#pragma unroll
    for (int qs = 0; qs < 2; ++qs) {
      uint32_t a = __builtin_bit_cast(uint32_t, dot[qs]), b = a;
      plswap(a, b);
      float part = (lane < 32) ? __builtin_bit_cast(float, b) : __builtin_bit_cast(float, a);
      float pe = exp2_fast(dot[qs] + part);
#pragma unroll
      for (int j = 0; j < 8; ++j) pef[qs].u[j] = 0;
      if (hi == 0) pef[qs].u[0] = f2bf(pe);
    }
#pragma unroll
    for (int dt = 0; dt < 2; ++dt) {
#pragma unroll
      for (int j = 0; j < 8; ++j) evf[dt].u[j] = 0;
      if (hi == 0) evf[dt].u[0] = evb[bn * 512 + h * 64 + dt * 32 + l31];
    }
    f32x16 z = {};
#pragma unroll
    for (int qs = 0; qs < 2; ++qs) {
#pragma unroll
      for (int dt = 0; dt < 2; ++dt)
        acc[qs][dt] = __builtin_amdgcn_mfma_f32_32x32x16_bf16(pef[qs].v, evf[dt].v, z, 0, 0, 0);
      acc5[qs] = __builtin_amdgcn_mfma_f32_32x32x16_bf16(pef[qs].v, bones1, z, 0, 0, 0);
    }
  }

  for (int jt = 0; jt < 16; ++jt) {
    __syncthreads();
    *(uint4*)(KlD) = kp0;
    *(uint4*)(KlD + 32 * 64) = kp1;
    *(uint4*)(VlD) = vp0;
    *(uint4*)(VlD + 32 * 64) = vp1;
    __syncthreads();

    if (jt < 15) {
      const int j0 = (jt + 1) * 64;
      kp0 = *(const uint4*)(KgA + (size_t)j0 * 512);
      kp1 = *(const uint4*)(KgA + (size_t)(j0 + 32) * 512);
      vp0 = *(const uint4*)(VgA + j0);
      vp1 = *(const uint4*)(VgA + j0 + (size_t)32 * 1024);
    }

#pragma unroll
    for (int sub = 0; sub < 2; ++sub) {
      const int rk = sub * 32 + l31;
      bf16x8 kb[4];
#pragma unroll
      for (int c = 0; c < 4; ++c)
        kb[c] = *(const bf16x8*)&Kl[rk * 64 + (((c * 2 + hi) ^ (rk & 7)) * 8)];

      f32x16 s[2] = {};
#pragma unroll
      for (int qs = 0; qs < 2; ++qs)
#pragma unroll
        for (int c = 0; c < 4; ++c)
          s[qs] = __builtin_amdgcn_mfma_f32_32x32x16_bf16(kb[c], qf[qs][c], s[qs], 0, 0, 0);

      bf16x8 pa[2][2];
#pragma unroll
      for (int qs = 0; qs < 2; ++qs) {
        uint32_t wd[8];
#pragma unroll
        for (int i = 0; i < 8; ++i)
          wd[i] = cvtpk(exp2_fast(s[qs][2 * i]), exp2_fast(s[qs][2 * i + 1]));
        plswap(wd[0], wd[2]);
        plswap(wd[1], wd[3]);
        plswap(wd[4], wd[6]);
        plswap(wd[5], wd[7]);
        union { uint32_t w[4]; bf16x8 v; } f0, f1;
        f0.w[0] = wd[0]; f0.w[1] = wd[1]; f0.w[2] = wd[2]; f0.w[3] = wd[3];
        f1.w[0] = wd[4]; f1.w[1] = wd[5]; f1.w[2] = wd[6]; f1.w[3] = wd[7];
        pa[qs][0] = f0.v;
        pa[qs][1] = f1.v;
      }

#pragma unroll
      for (int dt = 0; dt < 2; ++dt) {
        const int rv = dt * 32 + l31;
#pragma unroll
        for (int ch = 0; ch < 2; ++ch) {
          bf16x8 vb = *(const bf16x8*)&Vl[rv * 64 + (((sub * 4 + ch * 2 + hi) ^ (rv & 7)) * 8)];
#pragma unroll
          for (int qs = 0; qs < 2; ++qs)
            acc[qs][dt] = __builtin_amdgcn_mfma_f32_32x32x16_bf16(pa[qs][ch], vb, acc[qs][dt], 0, 0, 0);
        }
      }
#pragma unroll
      for (int qs = 0; qs < 2; ++qs)
#pragma unroll
        for (int ch = 0; ch < 2; ++ch)
          acc5[qs] = __builtin_amdgcn_mfma_f32_32x32x16_bf16(pa[qs][ch], bones1, acc5[qs], 0, 0, 0);
    }
  }

#pragma unroll
  for (int qs = 0; qs < 2; ++qs)
#pragma unroll
    for (int r = 0; r < 16; ++r) {
      const float inv = 1.0f / acc5[qs][r];
      const int q = q0 + qs * 32 + (r & 3) + 8 * (r >> 2) + 4 * hi;
      u16* op = Ob + (size_t)(bn * 1024 + q) * 512 + h * 64 + l31;
      op[0] = f2bf(acc[qs][0][r] * inv);
      op[32] = f2bf(acc[qs][1][r] * inv);
    }
}

// ---------------- launcher ----------------
extern "C" void kernel_launch(void* const* d_in, const int* in_sizes, int n_in,
                              void* d_out, int out_size, void* d_ws, size_t ws_size,
                              hipStream_t stream) {
  (void)in_sizes; (void)n_in; (void)out_size; (void)ws_size;
  const float* x     = (const float*)d_in[0];
  const float* label = (const float*)d_in[1];
  const float* Wqkv  = (const float*)d_in[2];
  const float* Wk    = (const float*)d_in[3];
  const float* Wv    = (const float*)d_in[4];
  const float* Wout  = (const float*)d_in[5];
  float* out = (float*)d_out;

  char* ws = (char*)d_ws;
  u16* xb    = (u16*)(ws);                 // 16 MB, reused as attention-out after GEMM1
  u16* WqkvT = (u16*)(ws + 16777216);      // 1.5 MB
  u16* WoutT = (u16*)(ws + 18350080);      // 0.5 MB
  u16* ekb   = (u16*)(ws + 18874368);      // 16 KB
  u16* evb   = (u16*)(ws + 18890752);      // 16 KB
  u16* Qbuf  = (u16*)(ws + 18907136);      // 16 MB
  u16* Kbuf  = (u16*)(ws + 35684352);      // 16 MB
  u16* VTbuf = (u16*)(ws + 52461568);      // 16 MB

  const float qscale = 0.125f * 1.4426950408889634f;

  prep_kernel<<<8448, 256, 0, stream>>>(x, Wqkv, Wout, label, Wk, Wv,
                                        xb, WqkvT, WoutT, ekb, evb, qscale);

  gemm_bt_kernel<0><<<1024, 256, 0, stream>>>(xb, WqkvT, Qbuf, Kbuf, VTbuf, nullptr, 512, 1536);

  attn_kernel<<<512, 256, 0, stream>>>(Qbuf, Kbuf, VTbuf, ekb, evb, xb);

  gemm_bt_kernel<1><<<512, 256, 0, stream>>>(xb, WoutT, nullptr, nullptr, nullptr, out, 512, 512);
}